// Round 2
// baseline (2942.484 us; speedup 1.0000x reference)
//
#include <hip/hip_runtime.h>
#include <float.h>

#define NG    32
#define PTS   1024
#define NPTS  (NG*PTS)      // 32768
#define KNN   30
#define DIM   64
#define CHUNK 8192

// ---------------------------------------------------------------------------
// prep: per-point sum of squares (f64) + transpose XT[f][p] for coalesced knn
// ---------------------------------------------------------------------------
template<int F>
__global__ __launch_bounds__(256) void prep_k(const float* __restrict__ X, int ldx,
                                              double* __restrict__ S, float* __restrict__ XT) {
    int p = blockIdx.x * 256 + threadIdx.x;
    double s = 0.0;
    #pragma unroll
    for (int f = 0; f < F; ++f) {
        float v = X[(size_t)p * ldx + f];
        s = fma((double)v, (double)v, s);
        XT[(size_t)f * NPTS + p] = v;
    }
    S[p] = s;
}

// ---------------------------------------------------------------------------
// knn: 1 wave per point, 4 points per 256-thread block.
// dist d(i,j) = s_i + s_j - 2*dot, computed in FP64 so the top-30 ordering
// matches the numpy (f64) reference exactly (fp32 cancellation flips the set).
// Each lane owns 16 j's. Selection: 30x min-extract of (dist, idx) with
// lower-index tie-break == lax.top_k semantics.
// ---------------------------------------------------------------------------
template<int F>
__global__ __launch_bounds__(256) void knn_k(const float* __restrict__ X, int ldx,
                                             const float* __restrict__ XT,
                                             const double* __restrict__ S,
                                             int* __restrict__ IDX) {
    int wv = threadIdx.x >> 6;
    int lane = threadIdx.x & 63;
    int i = blockIdx.x * 4 + wv;
    int base = i & ~(PTS - 1);
    __shared__ double xis[4][F];
    if (lane < F) xis[wv][lane] = (double)X[(size_t)i * ldx + lane];
    __syncthreads();
    double si = S[i];
    double dd[16];
    #pragma unroll
    for (int m = 0; m < 4; ++m) {
        int j0 = (m << 8) + (lane << 2);
        double d0 = 0.0, d1 = 0.0, d2 = 0.0, d3 = 0.0;
        #pragma unroll
        for (int f = 0; f < F; ++f) {
            double xif = xis[wv][f];
            const float4 xj = *reinterpret_cast<const float4*>(&XT[(size_t)f * NPTS + base + j0]);
            d0 = fma(xif, (double)xj.x, d0);
            d1 = fma(xif, (double)xj.y, d1);
            d2 = fma(xif, (double)xj.z, d2);
            d3 = fma(xif, (double)xj.w, d3);
        }
        dd[m * 4 + 0] = (si + S[base + j0 + 0]) - 2.0 * d0;
        dd[m * 4 + 1] = (si + S[base + j0 + 1]) - 2.0 * d1;
        dd[m * 4 + 2] = (si + S[base + j0 + 2]) - 2.0 * d2;
        dd[m * 4 + 3] = (si + S[base + j0 + 3]) - 2.0 * d3;
    }
    for (int k = 0; k < KNN; ++k) {
        double bd = DBL_MAX;
        int bj = 0x7fffffff;
        // local scan: for fixed lane, j is strictly increasing in r, so strict <
        // keeps the lowest index on exact ties.
        #pragma unroll
        for (int r = 0; r < 16; ++r) {
            int j = ((r >> 2) << 8) + (lane << 2) + (r & 3);
            if (dd[r] < bd) { bd = dd[r]; bj = j; }
        }
        #pragma unroll
        for (int off = 32; off; off >>= 1) {
            double od = __shfl_xor(bd, off);
            int oj = __shfl_xor(bj, off);
            if (od < bd || (od == bd && oj < bj)) { bd = od; bj = oj; }
        }
        if (((bj >> 2) & 63) == lane) {
            int r = ((bj >> 8) << 2) | (bj & 3);
            #pragma unroll
            for (int rr = 0; rr < 16; ++rr) if (rr == r) dd[rr] = DBL_MAX;
        }
        if (lane == 0) IDX[(size_t)i * KNN + k] = base + bj;
    }
}

// ---------------------------------------------------------------------------
// mg: per-point layer-1 decomposition.
//   m_i[c] = b1[c] + sum_f x_i[f]*(W1[f][c]-W1[F+f][c]);  g_i[c] = sum_f x_i[f]*W1[F+f][c]
// so edge h1 = relu(m_i + g_j).
// ---------------------------------------------------------------------------
template<int F>
__global__ __launch_bounds__(256) void mg_k(const float* __restrict__ X, int ldx,
                                            const float* __restrict__ W1,
                                            const float* __restrict__ B1,
                                            float* __restrict__ Mo, float* __restrict__ Go) {
    int tid = blockIdx.x * 256 + threadIdx.x;
    int pp = tid >> 6, c = tid & 63;
    float m = B1[c], g = 0.f;
    #pragma unroll
    for (int f = 0; f < F; ++f) {
        float xv = X[(size_t)pp * ldx + f];
        float wt = W1[f * DIM + c];
        float wb = W1[(F + f) * DIM + c];
        m = fmaf(xv, wt - wb, m);
        g = fmaf(xv, wb, g);
    }
    Mo[(size_t)pp * DIM + c] = m;
    Go[(size_t)pp * DIM + c] = g;
}

// ---------------------------------------------------------------------------
// edge: per point (1 wave each, 4/block): loop 30 neighbors:
//   h1 = relu(m_i + g_j); h2 = relu(b2 + h1 @ W2); out = max over neighbors
// ---------------------------------------------------------------------------
__global__ __launch_bounds__(256) void edge_k(const int* __restrict__ IDX,
                                              const float* __restrict__ G,
                                              const float* __restrict__ Mb,
                                              const float* __restrict__ W2,
                                              const float* __restrict__ B2,
                                              float* __restrict__ OUT, int ldo) {
    int wv = threadIdx.x >> 6, lane = threadIdx.x & 63;
    int i = blockIdx.x * 4 + wv;
    __shared__ __align__(16) float h1[4][DIM];
    float w2c[DIM];
    #pragma unroll
    for (int k2 = 0; k2 < DIM; ++k2) w2c[k2] = W2[k2 * DIM + lane];
    float mi = Mb[(size_t)i * DIM + lane];
    float b2c = B2[lane];
    float acc = -FLT_MAX;
    for (int nb = 0; nb < KNN; ++nb) {
        int j = IDX[(size_t)i * KNN + nb];
        float h = fmaxf(mi + G[(size_t)j * DIM + lane], 0.f);
        h1[wv][lane] = h;
        __syncthreads();
        float h2 = b2c;
        #pragma unroll
        for (int k2 = 0; k2 < DIM; k2 += 4) {
            const float4 hv = *reinterpret_cast<const float4*>(&h1[wv][k2]);
            h2 = fmaf(hv.x, w2c[k2 + 0], h2);
            h2 = fmaf(hv.y, w2c[k2 + 1], h2);
            h2 = fmaf(hv.z, w2c[k2 + 2], h2);
            h2 = fmaf(hv.w, w2c[k2 + 3], h2);
        }
        acc = fmaxf(acc, fmaxf(h2, 0.f));
        __syncthreads();
    }
    OUT[(size_t)i * ldo + lane] = acc;
}

// ---------------------------------------------------------------------------
// fp32 tiled GEMM: C[M x N] = act(A[M x Kd] @ W[Kd x N] + bias)
// 64x64 tile, BK=16, 256 threads, 4x4 microtile, A staged transposed in LDS.
// ---------------------------------------------------------------------------
template<bool RELU>
__global__ __launch_bounds__(256) void gemm_k(const float* __restrict__ A, int Kd,
                                              const float* __restrict__ W, int N,
                                              const float* __restrict__ Bias,
                                              float* __restrict__ C) {
    __shared__ __align__(16) float As_t[16][68];
    __shared__ __align__(16) float Ws[16][64];
    int bm = blockIdx.y * 64, bn = blockIdx.x * 64;
    int tid = threadIdx.x;
    int tr = tid >> 4, tc = tid & 15;
    float acc[4][4] = {};
    for (int k0 = 0; k0 < Kd; k0 += 16) {
        #pragma unroll
        for (int l = tid; l < 1024; l += 256) {
            int r = l >> 4, cc = l & 15;
            As_t[cc][r] = A[(size_t)(bm + r) * Kd + k0 + cc];
        }
        #pragma unroll
        for (int l = tid; l < 1024; l += 256) {
            int r = l >> 6, cc = l & 63;
            Ws[r][cc] = W[(size_t)(k0 + r) * N + bn + cc];
        }
        __syncthreads();
        #pragma unroll
        for (int kk = 0; kk < 16; ++kk) {
            const float4 av = *reinterpret_cast<const float4*>(&As_t[kk][tr << 2]);
            const float4 wvv = *reinterpret_cast<const float4*>(&Ws[kk][tc << 2]);
            float a4[4] = {av.x, av.y, av.z, av.w};
            float w4[4] = {wvv.x, wvv.y, wvv.z, wvv.w};
            #pragma unroll
            for (int u = 0; u < 4; ++u)
                #pragma unroll
                for (int v = 0; v < 4; ++v)
                    acc[u][v] = fmaf(a4[u], w4[v], acc[u][v]);
        }
        __syncthreads();
    }
    #pragma unroll
    for (int u = 0; u < 4; ++u) {
        int row = bm + (tr << 2) + u;
        float4 o;
        float b0 = Bias[bn + (tc << 2) + 0], b1 = Bias[bn + (tc << 2) + 1];
        float b2 = Bias[bn + (tc << 2) + 2], b3 = Bias[bn + (tc << 2) + 3];
        o.x = acc[u][0] + b0; o.y = acc[u][1] + b1;
        o.z = acc[u][2] + b2; o.w = acc[u][3] + b3;
        if (RELU) {
            o.x = fmaxf(o.x, 0.f); o.y = fmaxf(o.y, 0.f);
            o.z = fmaxf(o.z, 0.f); o.w = fmaxf(o.w, 0.f);
        }
        *reinterpret_cast<float4*>(&C[(size_t)row * N + bn + (tc << 2)]) = o;
    }
}

// ---------------------------------------------------------------------------
template<int F>
static void run_conv(const float* Xin, int ldx,
                     const float* W1, const float* B1,
                     const float* W2, const float* B2,
                     float* OUT, int ldo,
                     float* XT, double* S, float* Mb, float* Gb, int* IDX,
                     hipStream_t stream) {
    prep_k<F><<<NPTS / 256, 256, 0, stream>>>(Xin, ldx, S, XT);
    knn_k<F><<<NPTS / 4, 256, 0, stream>>>(Xin, ldx, XT, S, IDX);
    mg_k<F><<<NPTS * DIM / 256, 256, 0, stream>>>(Xin, ldx, W1, B1, Mb, Gb);
    edge_k<<<NPTS / 4, 256, 0, stream>>>(IDX, Gb, Mb, W2, B2, OUT, ldo);
}

extern "C" void kernel_launch(void* const* d_in, const int* in_sizes, int n_in,
                              void* d_out, int out_size, void* d_ws, size_t ws_size,
                              hipStream_t stream) {
    (void)in_sizes; (void)n_in; (void)out_size; (void)ws_size;
    const float* x    = (const float*)d_in[0];
    const float* c1w1 = (const float*)d_in[2];  const float* c1b1 = (const float*)d_in[3];
    const float* c1w2 = (const float*)d_in[4];  const float* c1b2 = (const float*)d_in[5];
    const float* c2w1 = (const float*)d_in[6];  const float* c2b1 = (const float*)d_in[7];
    const float* c2w2 = (const float*)d_in[8];  const float* c2b2 = (const float*)d_in[9];
    const float* c3w1 = (const float*)d_in[10]; const float* c3b1 = (const float*)d_in[11];
    const float* c3w2 = (const float*)d_in[12]; const float* c3b2 = (const float*)d_in[13];
    const float* lw   = (const float*)d_in[14]; const float* lb   = (const float*)d_in[15];
    const float* hw1  = (const float*)d_in[16]; const float* hb1  = (const float*)d_in[17];
    const float* hw2  = (const float*)d_in[18]; const float* hb2  = (const float*)d_in[19];
    const float* hw3  = (const float*)d_in[20]; const float* hb3  = (const float*)d_in[21];
    float* out = (float*)d_out;

    // workspace layout: XC | IDX | union(conv scratch, head scratch)
    float* XC  = (float*)d_ws;                       // 32768*192
    int*   IDX = (int*)(XC + (size_t)NPTS * 192);    // 32768*30
    float* SCR = (float*)(IDX + (size_t)NPTS * KNN); // byte offset %8 == 0
    // conv-phase view of SCR
    float*  XT = SCR;                                 // 64*32768 floats (even count)
    double* S  = (double*)(XT + (size_t)64 * NPTS);   // 32768 doubles, 8B-aligned
    float*  Mb = (float*)(S + NPTS);                  // 32768*64
    float*  Gb = Mb + (size_t)NPTS * DIM;             // 32768*64
    // head-phase view of SCR
    float* H1 = SCR;                        // CHUNK*1024
    float* H2 = H1 + (size_t)CHUNK * 1024;  // CHUNK*256
    float* H3 = H2 + (size_t)CHUNK * 256;   // CHUNK*128

    run_conv<14>(x,        14,  c1w1, c1b1, c1w2, c1b2, XC + 0,   192, XT, S, Mb, Gb, IDX, stream);
    run_conv<64>(XC + 0,   192, c2w1, c2b1, c2w2, c2b2, XC + 64,  192, XT, S, Mb, Gb, IDX, stream);
    run_conv<64>(XC + 64,  192, c3w1, c3b1, c3w2, c3b2, XC + 128, 192, XT, S, Mb, Gb, IDX, stream);

    for (int ch = 0; ch < 4; ++ch) {
        const float* a0 = XC + (size_t)ch * CHUNK * 192;
        float* o0 = out + (size_t)ch * CHUNK * 64;
        gemm_k<true ><<<dim3(1024 / 64, CHUNK / 64), 256, 0, stream>>>(a0, 192,  lw,  1024, lb,  H1);
        gemm_k<true ><<<dim3(256  / 64, CHUNK / 64), 256, 0, stream>>>(H1, 1024, hw1, 256,  hb1, H2);
        gemm_k<true ><<<dim3(128  / 64, CHUNK / 64), 256, 0, stream>>>(H2, 256,  hw2, 128,  hb2, H3);
        gemm_k<false><<<dim3(64   / 64, CHUNK / 64), 256, 0, stream>>>(H3, 128,  hw3, 64,   hb3, o0);
    }
}